// Round 5
// baseline (242.865 us; speedup 1.0000x reference)
//
#include <hip/hip_runtime.h>
#include <hip/hip_fp16.h>
#include <math.h>

#define N4C 32768
#define N3C 65536
#define N2C 131072
#define N1C 262144

typedef _Float16 f16x8 __attribute__((ext_vector_type(8)));
typedef float f32x4 __attribute__((ext_vector_type(4)));
typedef float f32x16 __attribute__((ext_vector_type(16)));

__device__ __forceinline__ f32x4 mfma16(f16x8 a, f16x8 b, f32x4 c) {
  return __builtin_amdgcn_mfma_f32_16x16x32_f16(a, b, c, 0, 0, 0);
}
__device__ __forceinline__ f32x16 mfma32(f16x8 a, f16x8 b, f32x16 c) {
  return __builtin_amdgcn_mfma_f32_32x32x16_f16(a, b, c, 0, 0, 0);
}

// fast celu (f32): max(x,0) + expm1(min(x,0)), branch-free
__device__ __forceinline__ float celuf(float x) {
  return fmaxf(x, 0.f) + (__expf(fminf(x, 0.f)) - 1.f);
}

__device__ __forceinline__ float logsigf(float x) {
  float e = __expf(-fabsf(x));
  return fminf(x, 0.f) - __logf(1.f + e);
}

__device__ __forceinline__ float max3f(float a, float b, float c) {
  return fmaxf(fmaxf(a, b), c);
}

// 2^x on f16 via v_exp_f16
__device__ __forceinline__ _Float16 exp2_16(_Float16 x) {
  __half h; __builtin_memcpy(&h, &x, 2);
  h = hexp2(h);
  _Float16 r; __builtin_memcpy(&r, &h, 2);
  return r;
}

// celu(x) + 1 = max(x,0) + exp(min(x,0)); the -1 is folded into the
// post-MFMA bias (bias -= sum_k Wb[k][n]), which commutes with edge-max.
__device__ __forceinline__ f16x8 celu8p1(f16x8 x) {
  f16x8 z = {};
  f16x8 mx = __builtin_elementwise_max(x, z);
  f16x8 mn = __builtin_elementwise_min(x, z) * (_Float16)1.44269504f;
#pragma unroll
  for (int i = 0; i < 8; ++i) mn[i] = exp2_16(mn[i]);
  return mx + mn;
}

// ---------------------------------------------------------------------------
// y4 = z @ W1a[:64] + b1a + pos4 @ W1a[64:67]  ([N4][64] f16)
// Fused tail blocks: vt3[p][k] = pos3[p] . W1a[64:67][k]  ([N3][64] f16)
// ---------------------------------------------------------------------------
__global__ __launch_bounds__(256) void y4_kernel(
    const float* __restrict__ z, const float* __restrict__ pos4,
    const float* __restrict__ pos3, const float* __restrict__ w1a,
    const float* __restrict__ b1a, _Float16* __restrict__ y4,
    _Float16* __restrict__ vt3) {
  if (blockIdx.x >= 512) {
    const int idx = (blockIdx.x - 512) * 256 + threadIdx.x;
    const int p = idx >> 3, seg = (idx & 7) * 8;
    const float q0 = pos3[p * 3 + 0];
    const float q1 = pos3[p * 3 + 1];
    const float q2 = pos3[p * 3 + 2];
    f16x8 v;
#pragma unroll
    for (int j = 0; j < 8; ++j) {
      const int k = seg + j;
      v[j] = (_Float16)(w1a[64 * 64 + k] * q0 + w1a[65 * 64 + k] * q1 +
                        w1a[66 * 64 + k] * q2);
    }
    *(f16x8*)(vt3 + (size_t)p * 64 + seg) = v;
    return;
  }
  const int lane = threadIdx.x & 63, wid = threadIdx.x >> 6;
  const int col = lane & 15, quad = lane >> 4;
  const int base = (blockIdx.x * 4 + wid) * 16;

  f16x8 Ba[2][4];
#pragma unroll
  for (int c = 0; c < 2; ++c)
#pragma unroll
    for (int t = 0; t < 4; ++t)
#pragma unroll
      for (int j = 0; j < 8; ++j)
        Ba[c][t][j] = (_Float16)w1a[(c * 32 + quad * 8 + j) * 64 + t * 16 + col];

  float wr[3][4];
#pragma unroll
  for (int c = 0; c < 3; ++c)
#pragma unroll
    for (int t = 0; t < 4; ++t)
      wr[c][t] = w1a[(64 + c) * 64 + t * 16 + col];

  float px[4], py[4], pz[4];
#pragma unroll
  for (int r = 0; r < 4; ++r) {
    const int row = base + quad * 4 + r;
    px[r] = pos4[row * 3 + 0];
    py[r] = pos4[row * 3 + 1];
    pz[r] = pos4[row * 3 + 2];
  }

  const float* zr = z + (size_t)(base + col) * 64;
  f16x8 A0, A1;
  {
    float4 f0 = *(const float4*)(zr + quad * 8);
    float4 f1 = *(const float4*)(zr + quad * 8 + 4);
    float4 f2 = *(const float4*)(zr + 32 + quad * 8);
    float4 f3 = *(const float4*)(zr + 32 + quad * 8 + 4);
    A0[0] = (_Float16)f0.x; A0[1] = (_Float16)f0.y; A0[2] = (_Float16)f0.z; A0[3] = (_Float16)f0.w;
    A0[4] = (_Float16)f1.x; A0[5] = (_Float16)f1.y; A0[6] = (_Float16)f1.z; A0[7] = (_Float16)f1.w;
    A1[0] = (_Float16)f2.x; A1[1] = (_Float16)f2.y; A1[2] = (_Float16)f2.z; A1[3] = (_Float16)f2.w;
    A1[4] = (_Float16)f3.x; A1[5] = (_Float16)f3.y; A1[6] = (_Float16)f3.z; A1[7] = (_Float16)f3.w;
  }
#pragma unroll
  for (int t = 0; t < 4; ++t) {
    f32x4 acc = {0.f, 0.f, 0.f, 0.f};
    acc = mfma16(A0, Ba[0][t], acc);
    acc = mfma16(A1, Ba[1][t], acc);
    const float bt = b1a[t * 16 + col];
#pragma unroll
    for (int r = 0; r < 4; ++r) {
      const float posterm =
          px[r] * wr[0][t] + py[r] * wr[1][t] + pz[r] * wr[2][t];
      y4[(size_t)(base + quad * 4 + r) * 64 + t * 16 + col] =
          (_Float16)(acc[r] + bt + posterm);
    }
  }
}

// ---------------------------------------------------------------------------
// y3 = x3 @ W2a[:32] + b2a + pos3 @ W2a[32:35]  ([N3][16] f16)
// Fused tail blocks: vt2[p][k] = pos2[p] . W2a[32:35][k]  ([N2][16] f16)
// ---------------------------------------------------------------------------
__global__ __launch_bounds__(256) void y3_kernel(
    const _Float16* __restrict__ x3f, const float* __restrict__ pos3,
    const float* __restrict__ pos2, const float* __restrict__ w2a,
    const float* __restrict__ b2a, _Float16* __restrict__ y3,
    _Float16* __restrict__ vt2) {
  if (blockIdx.x >= 1024) {
    const int idx = (blockIdx.x - 1024) * 256 + threadIdx.x;
    const int p = idx >> 1, seg = (idx & 1) * 8;
    const float q0 = pos2[p * 3 + 0];
    const float q1 = pos2[p * 3 + 1];
    const float q2 = pos2[p * 3 + 2];
    f16x8 v;
#pragma unroll
    for (int j = 0; j < 8; ++j) {
      const int k = seg + j;
      v[j] = (_Float16)(w2a[32 * 16 + k] * q0 + w2a[33 * 16 + k] * q1 +
                        w2a[34 * 16 + k] * q2);
    }
    *(f16x8*)(vt2 + (size_t)p * 16 + seg) = v;
    return;
  }
  const int lane = threadIdx.x & 63, wid = threadIdx.x >> 6;
  const int col = lane & 15, quad = lane >> 4;
  const int base = (blockIdx.x * 4 + wid) * 16;

  f16x8 B;
#pragma unroll
  for (int j = 0; j < 8; ++j) B[j] = (_Float16)w2a[(quad * 8 + j) * 16 + col];

  float wr[3];
#pragma unroll
  for (int c = 0; c < 3; ++c) wr[c] = w2a[(32 + c) * 16 + col];

  float px[4], py[4], pz[4];
#pragma unroll
  for (int r = 0; r < 4; ++r) {
    const int row = base + quad * 4 + r;
    px[r] = pos3[row * 3 + 0];
    py[r] = pos3[row * 3 + 1];
    pz[r] = pos3[row * 3 + 2];
  }

  f16x8 A = *(const f16x8*)(x3f + (size_t)(base + col) * 32 + quad * 8);
  f32x4 d = {0.f, 0.f, 0.f, 0.f};
  d = mfma16(A, B, d);
  const float bt = b2a[col];
#pragma unroll
  for (int r = 0; r < 4; ++r) {
    const float posterm = px[r] * wr[0] + py[r] * wr[1] + pz[r] * wr[2];
    y3[(size_t)(base + quad * 4 + r) * 16 + col] =
        (_Float16)(d[r] + bt + posterm);
  }
}

// ---------------------------------------------------------------------------
// y2 = x2 @ W3a[:16] + b3a + pos2 @ W3a[16:19]  ([N2][8] f16)
// Fused tail blocks: vt1[p][k] = pos1[p] . W3a[16:19][k]  ([N1][8] f16)
// ---------------------------------------------------------------------------
__global__ __launch_bounds__(256) void y2_kernel(
    const _Float16* __restrict__ x2f, const float* __restrict__ pos2,
    const float* __restrict__ pos1, const float* __restrict__ w3a,
    const float* __restrict__ b3a, _Float16* __restrict__ y2,
    _Float16* __restrict__ vt1) {
  if (blockIdx.x >= 2048) {
    const int p = (blockIdx.x - 2048) * 256 + threadIdx.x;
    const float q0 = pos1[p * 3 + 0];
    const float q1 = pos1[p * 3 + 1];
    const float q2 = pos1[p * 3 + 2];
    f16x8 v;
#pragma unroll
    for (int k = 0; k < 8; ++k)
      v[k] = (_Float16)(w3a[16 * 8 + k] * q0 + w3a[17 * 8 + k] * q1 +
                        w3a[18 * 8 + k] * q2);
    *(f16x8*)(vt1 + (size_t)p * 8) = v;
    return;
  }
  const int lane = threadIdx.x & 63, wid = threadIdx.x >> 6;
  const int col = lane & 15, quad = lane >> 4;
  const int base = (blockIdx.x * 4 + wid) * 16;

  f16x8 B;
#pragma unroll
  for (int j = 0; j < 8; ++j) {
    int k = quad * 8 + j;
    B[j] = (k < 16 && col < 8) ? (_Float16)w3a[k * 8 + col] : (_Float16)0.f;
  }
  f16x8 A = *(const f16x8*)(x2f + (size_t)(base + col) * 16 + (quad & 1) * 8);
  f32x4 d = {0.f, 0.f, 0.f, 0.f};
  d = mfma16(A, B, d);
  if (col < 8) {
    float wr[3];
#pragma unroll
    for (int c = 0; c < 3; ++c) wr[c] = w3a[(16 + c) * 8 + col];
    const float bt = b3a[col];
#pragma unroll
    for (int r = 0; r < 4; ++r) {
      const int row = base + quad * 4 + r;
      const float posterm = pos2[row * 3 + 0] * wr[0] +
                            pos2[row * 3 + 1] * wr[1] +
                            pos2[row * 3 + 2] * wr[2];
      y2[(size_t)row * 8 + col] = (_Float16)(d[r] + bt + posterm);
    }
  }
}

// ---------------------------------------------------------------------------
// Level 3 gather: 2 points/wave via mfma_32x32x16, vtab fold, src prefetch.
// launch_bounds(256,8) pins <=64 VGPR (8 waves/SIMD; the m69 cliff guard).
// ---------------------------------------------------------------------------
__device__ __forceinline__ void l3_body(
    int pb, int s1, int kh, int n, const _Float16* __restrict__ y4,
    const _Float16* __restrict__ vt3, const f16x8 Bb[4], float biasB,
    _Float16* __restrict__ x3f) {
  const int p = pb + (n >> 4);
  const _Float16* yrow = y4 + (size_t)s1 * 64 + kh * 8;
  const _Float16* vrow = vt3 + (size_t)p * 64 + kh * 8;

  f16x8 A[4];
#pragma unroll
  for (int ks = 0; ks < 4; ++ks)
    A[ks] = *(const f16x8*)(yrow + ks * 16) - *(const f16x8*)(vrow + ks * 16);
#pragma unroll
  for (int ks = 0; ks < 4; ++ks) A[ks] = celu8p1(A[ks]);

  f32x16 acc = {};
#pragma unroll
  for (int ks = 0; ks < 4; ++ks) acc = mfma32(A[ks], Bb[ks], acc);

  float mA = fmaxf(max3f(max3f(acc[0], acc[1], acc[2]),
                         max3f(acc[3], acc[4], acc[5]), acc[6]), acc[7]);
  float mB = fmaxf(max3f(max3f(acc[8], acc[9], acc[10]),
                         max3f(acc[11], acc[12], acc[13]), acc[14]), acc[15]);
  mA = fmaxf(mA, __shfl_xor(mA, 32, 64));
  mB = fmaxf(mB, __shfl_xor(mB, 32, 64));

  const float mv = kh ? mB : mA;
  x3f[(size_t)(pb + kh) * 32 + n] = (_Float16)celuf(mv + biasB);
}

__global__ __launch_bounds__(256, 8) void l3_kernel(
    const _Float16* __restrict__ y4, const _Float16* __restrict__ vt3,
    const int* __restrict__ src3, const float* __restrict__ w1b,
    const float* __restrict__ b1b, _Float16* __restrict__ x3f) {
  const int lane = threadIdx.x & 63, wid = threadIdx.x >> 6;
  const int n = lane & 31;   // B col (out channel) and A row (e + 16h)
  const int kh = lane >> 5;  // k-half

  f16x8 Bb[4];
#pragma unroll
  for (int ks = 0; ks < 4; ++ks)
#pragma unroll
    for (int j = 0; j < 8; ++j)
      Bb[ks][j] = (_Float16)w1b[(ks * 16 + kh * 8 + j) * 32 + n];

  // celu-shift fold, k distributed over kh halves
  float s = 0.f;
#pragma unroll 4
  for (int k = 0; k < 32; ++k) s += w1b[(kh * 32 + k) * 32 + n];
  s += __shfl_xor(s, 32, 64);
  const float biasB = b1b[n] - s;

  const int gwave = blockIdx.x * 4 + wid;
  const int nw = gridDim.x << 2;

  int sCur = src3[(2 * gwave) * 16 + n];
#pragma unroll 1
  for (int pb = 2 * gwave; pb < N3C; pb += 2 * nw) {
    const int pbn = pb + 2 * nw;
    const int pcl = (pbn < N3C) ? pbn : pb;  // clamp: redundant reload at tail
    const int sNext = src3[pcl * 16 + n];
    l3_body(pb, sCur, kh, n, y4, vt3, Bb, biasB, x3f);
    sCur = sNext;
  }
}

// ---------------------------------------------------------------------------
// Level 2 gather: 2-wide bodies + src prefetch rotation (VGPR-capped).
// ---------------------------------------------------------------------------
__device__ __forceinline__ void l2_compute(
    int pr, f16x8 A_in, f16x8 vt, f16x8 Bb, float biasB, int kh, int n,
    _Float16* __restrict__ x2f) {
  f16x8 A = celu8p1(A_in - vt);
  f32x16 acc = {};
  acc = mfma32(A, Bb, acc);

  float mA = fmaxf(max3f(max3f(acc[0], acc[1], acc[2]),
                         max3f(acc[3], acc[4], acc[5]), acc[6]), acc[7]);
  float mB = fmaxf(max3f(max3f(acc[8], acc[9], acc[10]),
                         max3f(acc[11], acc[12], acc[13]), acc[14]), acc[15]);
  mA = fmaxf(mA, __shfl_xor(mA, 32, 64));
  mB = fmaxf(mB, __shfl_xor(mB, 32, 64));

  if (n < 16) {
    const float m = kh ? mB : mA;
    x2f[(size_t)(2 * pr + kh) * 16 + n] = (_Float16)celuf(m + biasB);
  }
}

__global__ __launch_bounds__(256, 8) void l2_kernel(
    const _Float16* __restrict__ y3, const _Float16* __restrict__ vt2,
    const int* __restrict__ src2, const float* __restrict__ w2b,
    const float* __restrict__ b2b, _Float16* __restrict__ x2f) {
  const int lane = threadIdx.x & 63, wid = threadIdx.x >> 6;
  const int n = lane & 31;
  const int e = lane & 15;
  const int h = (lane >> 4) & 1;
  const int kh = lane >> 5;

  f16x8 Bb;
#pragma unroll
  for (int j = 0; j < 8; ++j)
    Bb[j] = (n < 16) ? (_Float16)w2b[(kh * 8 + j) * 16 + n] : (_Float16)0.f;
  float ws = 0.f;
#pragma unroll
  for (int k = 0; k < 16; ++k) ws += w2b[k * 16 + (n & 15)];
  const float biasB = b2b[n & 15] - ws;

  const int gwave = blockIdx.x * 4 + wid;
  const int nw = gridDim.x << 2;
  const int lim = N2C / 2;

  int sA = src2[(2 * gwave + h) * 16 + e];
  int sB = src2[(2 * (gwave + nw) + h) * 16 + e];

#pragma unroll 1
  for (int pr = gwave; pr < lim; pr += 2 * nw) {
    const int pr2 = pr + nw;  // always < lim (exact-fit schedule)
    const int pa = 2 * pr + h, pb2 = 2 * pr2 + h;

    f16x8 Aa = *(const f16x8*)(y3 + (size_t)sA * 16 + kh * 8);
    f16x8 va = *(const f16x8*)(vt2 + (size_t)pa * 16 + kh * 8);
    f16x8 Ab = *(const f16x8*)(y3 + (size_t)sB * 16 + kh * 8);
    f16x8 vb = *(const f16x8*)(vt2 + (size_t)pb2 * 16 + kh * 8);

    // prefetch next body's srcs (clamped at tail: redundant reload)
    const int prn = pr + 2 * nw;
    const int pc0 = (prn < lim) ? prn : pr;
    const int pc1 = (prn + nw < lim) ? prn + nw : pc0;
    const int sAn = src2[(2 * pc0 + h) * 16 + e];
    const int sBn = src2[(2 * pc1 + h) * 16 + e];

    l2_compute(pr,  Aa, va, Bb, biasB, kh, n, x2f);
    l2_compute(pr2, Ab, vb, Bb, biasB, kh, n, x2f);

    sA = sAn; sB = sBn;
  }
}

// ---------------------------------------------------------------------------
// Level 1 gather: 2-wide bodies + src prefetch rotation (VGPR-capped).
// ---------------------------------------------------------------------------
__device__ __forceinline__ void l1_compute(
    int pb, f16x8 A_in, f16x8 vt, f16x8 Bb, float biasB, float wl, float bl,
    int lane, float* __restrict__ out) {
  f16x8 A = celu8p1(A_in - vt);
  f32x16 acc = {};
  acc = mfma32(A, Bb, acc);

  float mA = fmaxf(max3f(max3f(acc[0], acc[1], acc[2]),
                         max3f(acc[3], acc[4], acc[5]), acc[6]), acc[7]);
  float mB = fmaxf(max3f(max3f(acc[8], acc[9], acc[10]),
                         max3f(acc[11], acc[12], acc[13]), acc[14]), acc[15]);
  mA = fmaxf(mA, __shfl_xor(mA, 32, 64));
  mB = fmaxf(mB, __shfl_xor(mB, 32, 64));

  float tA = celuf(mA + biasB) * wl;  // wl==0 for n>=16
  float tB = celuf(mB + biasB) * wl;
  tA += __shfl_xor(tA, 1, 64);
  tA += __shfl_xor(tA, 2, 64);
  tA += __shfl_xor(tA, 4, 64);
  tB += __shfl_xor(tB, 1, 64);
  tB += __shfl_xor(tB, 2, 64);
  tB += __shfl_xor(tB, 4, 64);
  if (lane == 0) {
    float2 o; o.x = logsigf(tA + bl); o.y = logsigf(tB + bl);
    *(float2*)(out + pb) = o;
  } else if (lane == 8) {
    float2 o; o.x = logsigf(tA + bl); o.y = logsigf(tB + bl);
    *(float2*)(out + pb + 2) = o;
  }
}

__global__ __launch_bounds__(256, 8) void l1_kernel(
    const _Float16* __restrict__ y2, const _Float16* __restrict__ vt1,
    const int* __restrict__ src1, const float* __restrict__ w3b,
    const float* __restrict__ b3b, const float* __restrict__ wlin,
    const float* __restrict__ blin, float* __restrict__ out) {
  const int lane = threadIdx.x & 63, wid = threadIdx.x >> 6;
  const int m = lane & 31;
  const int kh = lane >> 5;
  const int g = 2 * kh + ((lane >> 4) & 1);

  f16x8 Bb;
  const int n = m;
#pragma unroll
  for (int j = 0; j < 8; ++j)
    Bb[j] = (n < 16 && (n >> 3) == kh) ? (_Float16)w3b[j * 8 + (n & 7)]
                                       : (_Float16)0.f;
  float ws = 0.f;
#pragma unroll
  for (int j = 0; j < 8; ++j) ws += w3b[j * 8 + (n & 7)];
  const float biasB = (n < 16) ? b3b[n & 7] - ws : 0.f;
  const float wl = (n < 16) ? wlin[n & 7] : 0.f;
  const float bl = blin[0];

  const int gwave = blockIdx.x * 4 + wid;
  const int nw = gridDim.x << 2;
  const int lim = N1C / 4;

  // src1[q*64 + lane] covers the body's 4 points x 16 edges, coalesced
  int sA = src1[gwave * 64 + lane];
  int sB = src1[(gwave + nw) * 64 + lane];

#pragma unroll 1
  for (int q = gwave; q < lim; q += 2 * nw) {
    const int q2 = q + nw;  // always < lim (exact-fit schedule)
    const int p0 = q * 4 + g, p1 = q2 * 4 + g;

    f16x8 Aa = *(const f16x8*)(y2 + (size_t)sA * 8);
    f16x8 va = *(const f16x8*)(vt1 + (size_t)p0 * 8);
    f16x8 Ab = *(const f16x8*)(y2 + (size_t)sB * 8);
    f16x8 vb = *(const f16x8*)(vt1 + (size_t)p1 * 8);

    const int qn = q + 2 * nw;
    const int qc0 = (qn < lim) ? qn : q;
    const int qc1 = (qn + nw < lim) ? qn + nw : qc0;
    const int sAn = src1[qc0 * 64 + lane];
    const int sBn = src1[qc1 * 64 + lane];

    l1_compute(q * 4, Aa, va, Bb, biasB, wl, bl, lane, out);
    l1_compute(q2 * 4, Ab, vb, Bb, biasB, wl, bl, lane, out);

    sA = sAn; sB = sBn;
  }
}

extern "C" void kernel_launch(void* const* d_in, const int* in_sizes, int n_in,
                              void* d_out, int out_size, void* d_ws, size_t ws_size,
                              hipStream_t stream) {
  const float* z_mask = (const float*)d_in[0];
  const float* pos4 = (const float*)d_in[1];
  const float* pos3 = (const float*)d_in[2];
  const float* pos2 = (const float*)d_in[3];
  const float* pos1 = (const float*)d_in[4];
  const float* w1a = (const float*)d_in[9];
  const float* b1a = (const float*)d_in[10];
  const float* w1b = (const float*)d_in[11];
  const float* b1b = (const float*)d_in[12];
  const float* w2a = (const float*)d_in[13];
  const float* b2a = (const float*)d_in[14];
  const float* w2b = (const float*)d_in[15];
  const float* b2b = (const float*)d_in[16];
  const float* w3a = (const float*)d_in[17];
  const float* b3a = (const float*)d_in[18];
  const float* w3b = (const float*)d_in[19];
  const float* b3b = (const float*)d_in[20];
  const float* wlin = (const float*)d_in[21];
  const float* blin = (const float*)d_in[22];
  const int* src3 = (const int*)d_in[23];
  const int* src2 = (const int*)d_in[25];
  const int* src1 = (const int*)d_in[27];

  // ws (16 MB), lifetime-aliased:
  //   y4  [0,4M)   live y4k..l3      | vt3 [4M,12M) live y4k..l3
  //   x3f [12M,16M) live l3..y3k     | y3  [0,2M)   live y3k..l2
  //   vt2 [4M,8M)  live y3k..l2      | x2f [8M,12M) live l2..y2k
  //   y2  [2M,4M)  live y2k..l1      | vt1 [12M,16M) live y2k..l1
  char* w = (char*)d_ws;
  _Float16* y4  = (_Float16*)(w);
  _Float16* vt3 = (_Float16*)(w + (4u << 20));
  _Float16* x3f = (_Float16*)(w + (12u << 20));
  _Float16* y3  = (_Float16*)(w);
  _Float16* vt2 = (_Float16*)(w + (4u << 20));
  _Float16* x2f = (_Float16*)(w + (8u << 20));
  _Float16* y2  = (_Float16*)(w + (2u << 20));
  _Float16* vt1 = (_Float16*)(w + (12u << 20));
  float* out = (float*)d_out;

  y4_kernel<<<2560, 256, 0, stream>>>(z_mask, pos4, pos3, w1a, b1a, y4, vt3);
  l3_kernel<<<2048, 256, 0, stream>>>(y4, vt3, src3, w1b, b1b, x3f);
  y3_kernel<<<2048, 256, 0, stream>>>(x3f, pos3, pos2, w2a, b2a, y3, vt2);
  l2_kernel<<<2048, 256, 0, stream>>>(y3, vt2, src2, w2b, b2b, x2f);
  y2_kernel<<<3072, 256, 0, stream>>>(x2f, pos2, pos1, w3a, b3a, y2, vt1);
  l1_kernel<<<2048, 256, 0, stream>>>(y2, vt1, src1, w3b, b3b,
                                      wlin, blin, out);
}

// Round 6
// 240.356 us; speedup vs baseline: 1.0104x; 1.0104x over previous
//
#include <hip/hip_runtime.h>
#include <hip/hip_fp16.h>
#include <math.h>

#define N4C 32768
#define N3C 65536
#define N2C 131072
#define N1C 262144

typedef _Float16 f16x8 __attribute__((ext_vector_type(8)));
typedef float f32x2 __attribute__((ext_vector_type(2)));
typedef float f32x4 __attribute__((ext_vector_type(4)));
typedef float f32x16 __attribute__((ext_vector_type(16)));

__device__ __forceinline__ f32x4 mfma16(f16x8 a, f16x8 b, f32x4 c) {
  return __builtin_amdgcn_mfma_f32_16x16x32_f16(a, b, c, 0, 0, 0);
}
__device__ __forceinline__ f32x16 mfma32(f16x8 a, f16x8 b, f32x16 c) {
  return __builtin_amdgcn_mfma_f32_32x32x16_f16(a, b, c, 0, 0, 0);
}

// non-temporal (streaming) access helpers: data read/written exactly once —
// keep it OUT of L2 so the random y-table gathers stay resident.
__device__ __forceinline__ f16x8 ldnt8(const _Float16* p) {
  return __builtin_nontemporal_load((const f16x8*)p);
}
__device__ __forceinline__ int ldnti(const int* p) {
  return __builtin_nontemporal_load(p);
}

// fast celu (f32): max(x,0) + expm1(min(x,0)), branch-free
__device__ __forceinline__ float celuf(float x) {
  return fmaxf(x, 0.f) + (__expf(fminf(x, 0.f)) - 1.f);
}

__device__ __forceinline__ float logsigf(float x) {
  float e = __expf(-fabsf(x));
  return fminf(x, 0.f) - __logf(1.f + e);
}

__device__ __forceinline__ float max3f(float a, float b, float c) {
  return fmaxf(fmaxf(a, b), c);
}

// 2^x on f16 via v_exp_f16
__device__ __forceinline__ _Float16 exp2_16(_Float16 x) {
  __half h; __builtin_memcpy(&h, &x, 2);
  h = hexp2(h);
  _Float16 r; __builtin_memcpy(&r, &h, 2);
  return r;
}

// celu(x) + 1 = max(x,0) + exp(min(x,0)); the -1 is folded into the
// post-MFMA bias (bias -= sum_k Wb[k][n]), which commutes with edge-max.
__device__ __forceinline__ f16x8 celu8p1(f16x8 x) {
  f16x8 z = {};
  f16x8 mx = __builtin_elementwise_max(x, z);
  f16x8 mn = __builtin_elementwise_min(x, z) * (_Float16)1.44269504f;
#pragma unroll
  for (int i = 0; i < 8; ++i) mn[i] = exp2_16(mn[i]);
  return mx + mn;
}

// ---------------------------------------------------------------------------
// y4 = z @ W1a[:64] + b1a + pos4 @ W1a[64:67]  ([N4][64] f16)
// Fused tail blocks: vt3[p][k] = pos3[p] . W1a[64:67][k]  ([N3][64] f16)
// ---------------------------------------------------------------------------
__global__ __launch_bounds__(256) void y4_kernel(
    const float* __restrict__ z, const float* __restrict__ pos4,
    const float* __restrict__ pos3, const float* __restrict__ w1a,
    const float* __restrict__ b1a, _Float16* __restrict__ y4,
    _Float16* __restrict__ vt3) {
  if (blockIdx.x >= 512) {
    const int idx = (blockIdx.x - 512) * 256 + threadIdx.x;
    const int p = idx >> 3, seg = (idx & 7) * 8;
    const float q0 = pos3[p * 3 + 0];
    const float q1 = pos3[p * 3 + 1];
    const float q2 = pos3[p * 3 + 2];
    f16x8 v;
#pragma unroll
    for (int j = 0; j < 8; ++j) {
      const int k = seg + j;
      v[j] = (_Float16)(w1a[64 * 64 + k] * q0 + w1a[65 * 64 + k] * q1 +
                        w1a[66 * 64 + k] * q2);
    }
    *(f16x8*)(vt3 + (size_t)p * 64 + seg) = v;
    return;
  }
  const int lane = threadIdx.x & 63, wid = threadIdx.x >> 6;
  const int col = lane & 15, quad = lane >> 4;
  const int base = (blockIdx.x * 4 + wid) * 16;

  f16x8 Ba[2][4];
#pragma unroll
  for (int c = 0; c < 2; ++c)
#pragma unroll
    for (int t = 0; t < 4; ++t)
#pragma unroll
      for (int j = 0; j < 8; ++j)
        Ba[c][t][j] = (_Float16)w1a[(c * 32 + quad * 8 + j) * 64 + t * 16 + col];

  float wr[3][4];
#pragma unroll
  for (int c = 0; c < 3; ++c)
#pragma unroll
    for (int t = 0; t < 4; ++t)
      wr[c][t] = w1a[(64 + c) * 64 + t * 16 + col];

  float px[4], py[4], pz[4];
#pragma unroll
  for (int r = 0; r < 4; ++r) {
    const int row = base + quad * 4 + r;
    px[r] = pos4[row * 3 + 0];
    py[r] = pos4[row * 3 + 1];
    pz[r] = pos4[row * 3 + 2];
  }

  const float* zr = z + (size_t)(base + col) * 64;
  f16x8 A0, A1;
  {
    float4 f0 = *(const float4*)(zr + quad * 8);
    float4 f1 = *(const float4*)(zr + quad * 8 + 4);
    float4 f2 = *(const float4*)(zr + 32 + quad * 8);
    float4 f3 = *(const float4*)(zr + 32 + quad * 8 + 4);
    A0[0] = (_Float16)f0.x; A0[1] = (_Float16)f0.y; A0[2] = (_Float16)f0.z; A0[3] = (_Float16)f0.w;
    A0[4] = (_Float16)f1.x; A0[5] = (_Float16)f1.y; A0[6] = (_Float16)f1.z; A0[7] = (_Float16)f1.w;
    A1[0] = (_Float16)f2.x; A1[1] = (_Float16)f2.y; A1[2] = (_Float16)f2.z; A1[3] = (_Float16)f2.w;
    A1[4] = (_Float16)f3.x; A1[5] = (_Float16)f3.y; A1[6] = (_Float16)f3.z; A1[7] = (_Float16)f3.w;
  }
#pragma unroll
  for (int t = 0; t < 4; ++t) {
    f32x4 acc = {0.f, 0.f, 0.f, 0.f};
    acc = mfma16(A0, Ba[0][t], acc);
    acc = mfma16(A1, Ba[1][t], acc);
    const float bt = b1a[t * 16 + col];
#pragma unroll
    for (int r = 0; r < 4; ++r) {
      const float posterm =
          px[r] * wr[0][t] + py[r] * wr[1][t] + pz[r] * wr[2][t];
      y4[(size_t)(base + quad * 4 + r) * 64 + t * 16 + col] =
          (_Float16)(acc[r] + bt + posterm);
    }
  }
}

// ---------------------------------------------------------------------------
// y3 = x3 @ W2a[:32] + b2a + pos3 @ W2a[32:35]  ([N3][16] f16)
// Fused tail blocks: vt2[p][k] = pos2[p] . W2a[32:35][k]  ([N2][16] f16)
// ---------------------------------------------------------------------------
__global__ __launch_bounds__(256) void y3_kernel(
    const _Float16* __restrict__ x3f, const float* __restrict__ pos3,
    const float* __restrict__ pos2, const float* __restrict__ w2a,
    const float* __restrict__ b2a, _Float16* __restrict__ y3,
    _Float16* __restrict__ vt2) {
  if (blockIdx.x >= 1024) {
    const int idx = (blockIdx.x - 1024) * 256 + threadIdx.x;
    const int p = idx >> 1, seg = (idx & 1) * 8;
    const float q0 = pos2[p * 3 + 0];
    const float q1 = pos2[p * 3 + 1];
    const float q2 = pos2[p * 3 + 2];
    f16x8 v;
#pragma unroll
    for (int j = 0; j < 8; ++j) {
      const int k = seg + j;
      v[j] = (_Float16)(w2a[32 * 16 + k] * q0 + w2a[33 * 16 + k] * q1 +
                        w2a[34 * 16 + k] * q2);
    }
    *(f16x8*)(vt2 + (size_t)p * 16 + seg) = v;
    return;
  }
  const int lane = threadIdx.x & 63, wid = threadIdx.x >> 6;
  const int col = lane & 15, quad = lane >> 4;
  const int base = (blockIdx.x * 4 + wid) * 16;

  f16x8 B;
#pragma unroll
  for (int j = 0; j < 8; ++j) B[j] = (_Float16)w2a[(quad * 8 + j) * 16 + col];

  float wr[3];
#pragma unroll
  for (int c = 0; c < 3; ++c) wr[c] = w2a[(32 + c) * 16 + col];

  float px[4], py[4], pz[4];
#pragma unroll
  for (int r = 0; r < 4; ++r) {
    const int row = base + quad * 4 + r;
    px[r] = pos3[row * 3 + 0];
    py[r] = pos3[row * 3 + 1];
    pz[r] = pos3[row * 3 + 2];
  }

  f16x8 A = *(const f16x8*)(x3f + (size_t)(base + col) * 32 + quad * 8);
  f32x4 d = {0.f, 0.f, 0.f, 0.f};
  d = mfma16(A, B, d);
  const float bt = b2a[col];
#pragma unroll
  for (int r = 0; r < 4; ++r) {
    const float posterm = px[r] * wr[0] + py[r] * wr[1] + pz[r] * wr[2];
    y3[(size_t)(base + quad * 4 + r) * 16 + col] =
        (_Float16)(d[r] + bt + posterm);
  }
}

// ---------------------------------------------------------------------------
// y2 = x2 @ W3a[:16] + b3a + pos2 @ W3a[16:19]  ([N2][8] f16)
// Fused tail blocks: vt1[p][k] = pos1[p] . W3a[16:19][k]  ([N1][8] f16)
// ---------------------------------------------------------------------------
__global__ __launch_bounds__(256) void y2_kernel(
    const _Float16* __restrict__ x2f, const float* __restrict__ pos2,
    const float* __restrict__ pos1, const float* __restrict__ w3a,
    const float* __restrict__ b3a, _Float16* __restrict__ y2,
    _Float16* __restrict__ vt1) {
  if (blockIdx.x >= 2048) {
    const int p = (blockIdx.x - 2048) * 256 + threadIdx.x;
    const float q0 = pos1[p * 3 + 0];
    const float q1 = pos1[p * 3 + 1];
    const float q2 = pos1[p * 3 + 2];
    f16x8 v;
#pragma unroll
    for (int k = 0; k < 8; ++k)
      v[k] = (_Float16)(w3a[16 * 8 + k] * q0 + w3a[17 * 8 + k] * q1 +
                        w3a[18 * 8 + k] * q2);
    *(f16x8*)(vt1 + (size_t)p * 8) = v;
    return;
  }
  const int lane = threadIdx.x & 63, wid = threadIdx.x >> 6;
  const int col = lane & 15, quad = lane >> 4;
  const int base = (blockIdx.x * 4 + wid) * 16;

  f16x8 B;
#pragma unroll
  for (int j = 0; j < 8; ++j) {
    int k = quad * 8 + j;
    B[j] = (k < 16 && col < 8) ? (_Float16)w3a[k * 8 + col] : (_Float16)0.f;
  }
  f16x8 A = *(const f16x8*)(x2f + (size_t)(base + col) * 16 + (quad & 1) * 8);
  f32x4 d = {0.f, 0.f, 0.f, 0.f};
  d = mfma16(A, B, d);
  if (col < 8) {
    float wr[3];
#pragma unroll
    for (int c = 0; c < 3; ++c) wr[c] = w3a[(16 + c) * 8 + col];
    const float bt = b3a[col];
#pragma unroll
    for (int r = 0; r < 4; ++r) {
      const int row = base + quad * 4 + r;
      const float posterm = pos2[row * 3 + 0] * wr[0] +
                            pos2[row * 3 + 1] * wr[1] +
                            pos2[row * 3 + 2] * wr[2];
      y2[(size_t)row * 8 + col] = (_Float16)(d[r] + bt + posterm);
    }
  }
}

// ---------------------------------------------------------------------------
// Level 3 gather: 2 points/wave via mfma_32x32x16, vtab position fold.
// Streams (src3, vt3) are non-temporal; only the randomly-gathered y4 table
// competes for L2 residency.
// ---------------------------------------------------------------------------
__global__ __launch_bounds__(256) void l3_kernel(
    const _Float16* __restrict__ y4, const _Float16* __restrict__ vt3,
    const int* __restrict__ src3, const float* __restrict__ w1b,
    const float* __restrict__ b1b, _Float16* __restrict__ x3f) {
  const int lane = threadIdx.x & 63, wid = threadIdx.x >> 6;
  const int n = lane & 31;   // B col (out channel) and A row (e + 16h)
  const int kh = lane >> 5;  // k-half

  // B frags: B[ks][j] = w1b[k][n], k = ks*16 + kh*8 + j
  f16x8 Bb[4];
#pragma unroll
  for (int ks = 0; ks < 4; ++ks)
#pragma unroll
    for (int j = 0; j < 8; ++j)
      Bb[ks][j] = (_Float16)w1b[(ks * 16 + kh * 8 + j) * 32 + n];

  // celu-shift fold: biasB = b1b[n] - sum_k w1b[k][n]; k distributed over kh
  float s = 0.f;
#pragma unroll 4
  for (int k = 0; k < 32; ++k) s += w1b[(kh * 32 + k) * 32 + n];
  s += __shfl_xor(s, 32, 64);
  const float biasB = b1b[n] - s;

  const int gwave = blockIdx.x * 4 + wid;
  const int nw = gridDim.x << 2;

#pragma unroll 1
  for (int pb = gwave * 2; pb < N3C; pb += nw * 2) {
    const int s1 = ldnti(src3 + pb * 16 + n);  // coalesced stream, nt
    const int p = pb + (n >> 4);
    const _Float16* yrow = y4 + (size_t)s1 * 64 + kh * 8;
    const _Float16* vrow = vt3 + (size_t)p * 64 + kh * 8;

    f16x8 A[4];
#pragma unroll
    for (int ks = 0; ks < 4; ++ks)
      A[ks] = *(const f16x8*)(yrow + ks * 16) - ldnt8(vrow + ks * 16);
#pragma unroll
    for (int ks = 0; ks < 4; ++ks) A[ks] = celu8p1(A[ks]);

    f32x16 acc = {};
#pragma unroll
    for (int ks = 0; ks < 4; ++ks) acc = mfma32(A[ks], Bb[ks], acc);

    // regs 0..7 -> rows <16 (point pb), regs 8..15 -> rows >=16 (point pb+1)
    float mA = fmaxf(max3f(max3f(acc[0], acc[1], acc[2]),
                           max3f(acc[3], acc[4], acc[5]), acc[6]), acc[7]);
    float mB = fmaxf(max3f(max3f(acc[8], acc[9], acc[10]),
                           max3f(acc[11], acc[12], acc[13]), acc[14]), acc[15]);
    mA = fmaxf(mA, __shfl_xor(mA, 32, 64));
    mB = fmaxf(mB, __shfl_xor(mB, 32, 64));

    const float mv = kh ? mB : mA;
    x3f[(size_t)(pb + kh) * 32 + n] = (_Float16)celuf(mv + biasB);
  }
}

// ---------------------------------------------------------------------------
// Level 2 gather, pair-pipelined: 2 points/wave via mfma_32x32x16, vtab fold.
// src2/vt2 non-temporal.
// ---------------------------------------------------------------------------
__device__ __forceinline__ void l2_compute(
    int pr, f16x8 A_in, f16x8 vt, f16x8 Bb, float biasB, int kh, int n,
    _Float16* __restrict__ x2f) {
  f16x8 A = celu8p1(A_in - vt);
  f32x16 acc = {};
  acc = mfma32(A, Bb, acc);

  float mA = fmaxf(max3f(max3f(acc[0], acc[1], acc[2]),
                         max3f(acc[3], acc[4], acc[5]), acc[6]), acc[7]);
  float mB = fmaxf(max3f(max3f(acc[8], acc[9], acc[10]),
                         max3f(acc[11], acc[12], acc[13]), acc[14]), acc[15]);
  mA = fmaxf(mA, __shfl_xor(mA, 32, 64));
  mB = fmaxf(mB, __shfl_xor(mB, 32, 64));

  if (n < 16) {
    const float m = kh ? mB : mA;
    x2f[(size_t)(2 * pr + kh) * 16 + n] = (_Float16)celuf(m + biasB);
  }
}

__global__ __launch_bounds__(256) void l2_kernel(
    const _Float16* __restrict__ y3, const _Float16* __restrict__ vt2,
    const int* __restrict__ src2, const float* __restrict__ w2b,
    const float* __restrict__ b2b, _Float16* __restrict__ x2f) {
  const int lane = threadIdx.x & 63, wid = threadIdx.x >> 6;
  const int n = lane & 31;
  const int e = lane & 15;
  const int h = (lane >> 4) & 1;
  const int kh = lane >> 5;

  f16x8 Bb;
#pragma unroll
  for (int j = 0; j < 8; ++j)
    Bb[j] = (n < 16) ? (_Float16)w2b[(kh * 8 + j) * 16 + n] : (_Float16)0.f;
  // celu-shift fold
  float ws = 0.f;
#pragma unroll
  for (int k = 0; k < 16; ++k) ws += w2b[k * 16 + (n & 15)];
  const float biasB = b2b[n & 15] - ws;

  const int gwave = blockIdx.x * 4 + wid;
  const int nw = gridDim.x << 2;

#pragma unroll 1
  for (int pr = gwave; pr < N2C / 2; pr += 2 * nw) {
    const int pr2 = pr + nw;
    const int pa = 2 * pr + h, pb = 2 * pr2 + h;
    const int sa = ldnti(src2 + pa * 16 + e);
    const int sb = ldnti(src2 + pb * 16 + e);

    f16x8 Aa = *(const f16x8*)(y3 + (size_t)sa * 16 + kh * 8);
    f16x8 Ab = *(const f16x8*)(y3 + (size_t)sb * 16 + kh * 8);
    f16x8 va = ldnt8(vt2 + (size_t)pa * 16 + kh * 8);
    f16x8 vb = ldnt8(vt2 + (size_t)pb * 16 + kh * 8);

    l2_compute(pr,  Aa, va, Bb, biasB, kh, n, x2f);
    l2_compute(pr2, Ab, vb, Bb, biasB, kh, n, x2f);
  }
}

// ---------------------------------------------------------------------------
// Level 1 gather, pair-pipelined: 4 points/wave via block-diag mfma_32x32x16,
// vtab position fold. src1/vt1 non-temporal; out store non-temporal.
// ---------------------------------------------------------------------------
__device__ __forceinline__ void l1_compute(
    int pb, f16x8 A_in, f16x8 vt, f16x8 Bb, float biasB, float wl, float bl,
    int lane, float* __restrict__ out) {
  f16x8 A = celu8p1(A_in - vt);
  f32x16 acc = {};
  acc = mfma32(A, Bb, acc);

  float mA = fmaxf(max3f(max3f(acc[0], acc[1], acc[2]),
                         max3f(acc[3], acc[4], acc[5]), acc[6]), acc[7]);
  float mB = fmaxf(max3f(max3f(acc[8], acc[9], acc[10]),
                         max3f(acc[11], acc[12], acc[13]), acc[14]), acc[15]);
  mA = fmaxf(mA, __shfl_xor(mA, 32, 64));
  mB = fmaxf(mB, __shfl_xor(mB, 32, 64));

  float tA = celuf(mA + biasB) * wl;  // wl==0 for n>=16
  float tB = celuf(mB + biasB) * wl;
  tA += __shfl_xor(tA, 1, 64);
  tA += __shfl_xor(tA, 2, 64);
  tA += __shfl_xor(tA, 4, 64);
  tB += __shfl_xor(tB, 1, 64);
  tB += __shfl_xor(tB, 2, 64);
  tB += __shfl_xor(tB, 4, 64);
  if (lane == 0) {
    f32x2 o; o[0] = logsigf(tA + bl); o[1] = logsigf(tB + bl);
    __builtin_nontemporal_store(o, (f32x2*)(out + pb));
  } else if (lane == 8) {
    f32x2 o; o[0] = logsigf(tA + bl); o[1] = logsigf(tB + bl);
    __builtin_nontemporal_store(o, (f32x2*)(out + pb + 2));
  }
}

__global__ __launch_bounds__(256) void l1_kernel(
    const _Float16* __restrict__ y2, const _Float16* __restrict__ vt1,
    const int* __restrict__ src1, const float* __restrict__ w3b,
    const float* __restrict__ b3b, const float* __restrict__ wlin,
    const float* __restrict__ blin, float* __restrict__ out) {
  const int lane = threadIdx.x & 63, wid = threadIdx.x >> 6;
  const int m = lane & 31;
  const int kh = lane >> 5;
  const int g = 2 * kh + ((lane >> 4) & 1);

  f16x8 Bb;
  const int n = m;
#pragma unroll
  for (int j = 0; j < 8; ++j)
    Bb[j] = (n < 16 && (n >> 3) == kh) ? (_Float16)w3b[j * 8 + (n & 7)]
                                       : (_Float16)0.f;
  float ws = 0.f;
#pragma unroll
  for (int j = 0; j < 8; ++j) ws += w3b[j * 8 + (n & 7)];
  const float biasB = (n < 16) ? b3b[n & 7] - ws : 0.f;
  const float wl = (n < 16) ? wlin[n & 7] : 0.f;
  const float bl = blin[0];

  const int gwave = blockIdx.x * 4 + wid;
  const int nw = gridDim.x << 2;

#pragma unroll 1
  for (int q = gwave; q < N1C / 4; q += 2 * nw) {
    const int q2 = q + nw;
    const int pba = q * 4, pbb = q2 * 4;
    const int pa = pba + g, pb = pbb + g;
    // src1[q*64 + lane]: 4 points x 16 edges, fully coalesced stream
    const int sa = ldnti(src1 + q * 64 + lane);
    const int sb = ldnti(src1 + q2 * 64 + lane);

    f16x8 Aa = *(const f16x8*)(y2 + (size_t)sa * 8);
    f16x8 Ab = *(const f16x8*)(y2 + (size_t)sb * 8);
    f16x8 va = ldnt8(vt1 + (size_t)pa * 8);
    f16x8 vb = ldnt8(vt1 + (size_t)pb * 8);

    l1_compute(pba, Aa, va, Bb, biasB, wl, bl, lane, out);
    l1_compute(pbb, Ab, vb, Bb, biasB, wl, bl, lane, out);
  }
}

extern "C" void kernel_launch(void* const* d_in, const int* in_sizes, int n_in,
                              void* d_out, int out_size, void* d_ws, size_t ws_size,
                              hipStream_t stream) {
  const float* z_mask = (const float*)d_in[0];
  const float* pos4 = (const float*)d_in[1];
  const float* pos3 = (const float*)d_in[2];
  const float* pos2 = (const float*)d_in[3];
  const float* pos1 = (const float*)d_in[4];
  const float* w1a = (const float*)d_in[9];
  const float* b1a = (const float*)d_in[10];
  const float* w1b = (const float*)d_in[11];
  const float* b1b = (const float*)d_in[12];
  const float* w2a = (const float*)d_in[13];
  const float* b2a = (const float*)d_in[14];
  const float* w2b = (const float*)d_in[15];
  const float* b2b = (const float*)d_in[16];
  const float* w3a = (const float*)d_in[17];
  const float* b3a = (const float*)d_in[18];
  const float* w3b = (const float*)d_in[19];
  const float* b3b = (const float*)d_in[20];
  const float* wlin = (const float*)d_in[21];
  const float* blin = (const float*)d_in[22];
  const int* src3 = (const int*)d_in[23];
  const int* src2 = (const int*)d_in[25];
  const int* src1 = (const int*)d_in[27];

  // ws (16 MB), lifetime-aliased:
  //   y4  [0,4M)   live y4k..l3      | vt3 [4M,12M) live y4k..l3
  //   x3f [12M,16M) live l3..y3k     | y3  [0,2M)   live y3k..l2
  //   vt2 [4M,8M)  live y3k..l2      | x2f [8M,12M) live l2..y2k
  //   y2  [2M,4M)  live y2k..l1      | vt1 [12M,16M) live y2k..l1
  char* w = (char*)d_ws;
  _Float16* y4  = (_Float16*)(w);
  _Float16* vt3 = (_Float16*)(w + (4u << 20));
  _Float16* x3f = (_Float16*)(w + (12u << 20));
  _Float16* y3  = (_Float16*)(w);
  _Float16* vt2 = (_Float16*)(w + (4u << 20));
  _Float16* x2f = (_Float16*)(w + (8u << 20));
  _Float16* y2  = (_Float16*)(w + (2u << 20));
  _Float16* vt1 = (_Float16*)(w + (12u << 20));
  float* out = (float*)d_out;

  y4_kernel<<<2560, 256, 0, stream>>>(z_mask, pos4, pos3, w1a, b1a, y4, vt3);
  l3_kernel<<<2048, 256, 0, stream>>>(y4, vt3, src3, w1b, b1b, x3f);
  y3_kernel<<<2048, 256, 0, stream>>>(x3f, pos3, pos2, w2a, b2a, y3, vt2);
  l2_kernel<<<2048, 256, 0, stream>>>(y3, vt2, src2, w2b, b2b, x2f);
  y2_kernel<<<3072, 256, 0, stream>>>(x2f, pos2, pos1, w3a, b3a, y2, vt1);
  l1_kernel<<<2048, 256, 0, stream>>>(y2, vt1, src1, w3b, b3b,
                                      wlin, blin, out);
}

// Round 8
// 234.786 us; speedup vs baseline: 1.0344x; 1.0237x over previous
//
#include <hip/hip_runtime.h>
#include <hip/hip_fp16.h>
#include <math.h>

#define N4C 32768
#define N3C 65536
#define N2C 131072
#define N1C 262144

typedef _Float16 f16x8 __attribute__((ext_vector_type(8)));
typedef float f32x4 __attribute__((ext_vector_type(4)));
typedef float f32x16 __attribute__((ext_vector_type(16)));

__device__ __forceinline__ f32x4 mfma16(f16x8 a, f16x8 b, f32x4 c) {
  return __builtin_amdgcn_mfma_f32_16x16x32_f16(a, b, c, 0, 0, 0);
}
__device__ __forceinline__ f32x16 mfma32(f16x8 a, f16x8 b, f32x16 c) {
  return __builtin_amdgcn_mfma_f32_32x32x16_f16(a, b, c, 0, 0, 0);
}

// fast celu (f32): max(x,0) + expm1(min(x,0)), branch-free
__device__ __forceinline__ float celuf(float x) {
  return fmaxf(x, 0.f) + (__expf(fminf(x, 0.f)) - 1.f);
}

__device__ __forceinline__ float logsigf(float x) {
  float e = __expf(-fabsf(x));
  return fminf(x, 0.f) - __logf(1.f + e);
}

__device__ __forceinline__ float max3f(float a, float b, float c) {
  return fmaxf(fmaxf(a, b), c);
}

// 2^x on f16 via v_exp_f16
__device__ __forceinline__ _Float16 exp2_16(_Float16 x) {
  __half h; __builtin_memcpy(&h, &x, 2);
  h = hexp2(h);
  _Float16 r; __builtin_memcpy(&r, &h, 2);
  return r;
}

// celu(x) + 1 = max(x,0) + exp(min(x,0)); the -1 is folded into the
// post-MFMA bias (bias -= sum_k Wb[k][n]), which commutes with edge-max.
__device__ __forceinline__ f16x8 celu8p1(f16x8 x) {
  f16x8 z = {};
  f16x8 mx = __builtin_elementwise_max(x, z);
  f16x8 mn = __builtin_elementwise_min(x, z) * (_Float16)1.44269504f;
#pragma unroll
  for (int i = 0; i < 8; ++i) mn[i] = exp2_16(mn[i]);
  return mx + mn;
}

// ---------------------------------------------------------------------------
// y4 = z @ W1a[:64] + b1a + pos4 @ W1a[64:67]  ([N4][64] f16)
// Fused tail blocks: vt3[p][k] = pos3[p] . W1a[64:67][k]  ([N3][64] f16)
// ---------------------------------------------------------------------------
__global__ __launch_bounds__(256) void y4_kernel(
    const float* __restrict__ z, const float* __restrict__ pos4,
    const float* __restrict__ pos3, const float* __restrict__ w1a,
    const float* __restrict__ b1a, _Float16* __restrict__ y4,
    _Float16* __restrict__ vt3) {
  if (blockIdx.x >= 512) {
    const int idx = (blockIdx.x - 512) * 256 + threadIdx.x;
    const int p = idx >> 3, seg = (idx & 7) * 8;
    const float q0 = pos3[p * 3 + 0];
    const float q1 = pos3[p * 3 + 1];
    const float q2 = pos3[p * 3 + 2];
    f16x8 v;
#pragma unroll
    for (int j = 0; j < 8; ++j) {
      const int k = seg + j;
      v[j] = (_Float16)(w1a[64 * 64 + k] * q0 + w1a[65 * 64 + k] * q1 +
                        w1a[66 * 64 + k] * q2);
    }
    *(f16x8*)(vt3 + (size_t)p * 64 + seg) = v;
    return;
  }
  const int lane = threadIdx.x & 63, wid = threadIdx.x >> 6;
  const int col = lane & 15, quad = lane >> 4;
  const int base = (blockIdx.x * 4 + wid) * 16;

  f16x8 Ba[2][4];
#pragma unroll
  for (int c = 0; c < 2; ++c)
#pragma unroll
    for (int t = 0; t < 4; ++t)
#pragma unroll
      for (int j = 0; j < 8; ++j)
        Ba[c][t][j] = (_Float16)w1a[(c * 32 + quad * 8 + j) * 64 + t * 16 + col];

  float wr[3][4];
#pragma unroll
  for (int c = 0; c < 3; ++c)
#pragma unroll
    for (int t = 0; t < 4; ++t)
      wr[c][t] = w1a[(64 + c) * 64 + t * 16 + col];

  float px[4], py[4], pz[4];
#pragma unroll
  for (int r = 0; r < 4; ++r) {
    const int row = base + quad * 4 + r;
    px[r] = pos4[row * 3 + 0];
    py[r] = pos4[row * 3 + 1];
    pz[r] = pos4[row * 3 + 2];
  }

  const float* zr = z + (size_t)(base + col) * 64;
  f16x8 A0, A1;
  {
    float4 f0 = *(const float4*)(zr + quad * 8);
    float4 f1 = *(const float4*)(zr + quad * 8 + 4);
    float4 f2 = *(const float4*)(zr + 32 + quad * 8);
    float4 f3 = *(const float4*)(zr + 32 + quad * 8 + 4);
    A0[0] = (_Float16)f0.x; A0[1] = (_Float16)f0.y; A0[2] = (_Float16)f0.z; A0[3] = (_Float16)f0.w;
    A0[4] = (_Float16)f1.x; A0[5] = (_Float16)f1.y; A0[6] = (_Float16)f1.z; A0[7] = (_Float16)f1.w;
    A1[0] = (_Float16)f2.x; A1[1] = (_Float16)f2.y; A1[2] = (_Float16)f2.z; A1[3] = (_Float16)f2.w;
    A1[4] = (_Float16)f3.x; A1[5] = (_Float16)f3.y; A1[6] = (_Float16)f3.z; A1[7] = (_Float16)f3.w;
  }
#pragma unroll
  for (int t = 0; t < 4; ++t) {
    f32x4 acc = {0.f, 0.f, 0.f, 0.f};
    acc = mfma16(A0, Ba[0][t], acc);
    acc = mfma16(A1, Ba[1][t], acc);
    const float bt = b1a[t * 16 + col];
#pragma unroll
    for (int r = 0; r < 4; ++r) {
      const float posterm =
          px[r] * wr[0][t] + py[r] * wr[1][t] + pz[r] * wr[2][t];
      y4[(size_t)(base + quad * 4 + r) * 64 + t * 16 + col] =
          (_Float16)(acc[r] + bt + posterm);
    }
  }
}

// ---------------------------------------------------------------------------
// y3 = x3 @ W2a[:32] + b2a + pos3 @ W2a[32:35]  ([N3][16] f16)
// Fused tail blocks: vt2[p][k] = pos2[p] . W2a[32:35][k]  ([N2][16] f16)
// ---------------------------------------------------------------------------
__global__ __launch_bounds__(256) void y3_kernel(
    const _Float16* __restrict__ x3f, const float* __restrict__ pos3,
    const float* __restrict__ pos2, const float* __restrict__ w2a,
    const float* __restrict__ b2a, _Float16* __restrict__ y3,
    _Float16* __restrict__ vt2) {
  if (blockIdx.x >= 1024) {
    const int idx = (blockIdx.x - 1024) * 256 + threadIdx.x;
    const int p = idx >> 1, seg = (idx & 1) * 8;
    const float q0 = pos2[p * 3 + 0];
    const float q1 = pos2[p * 3 + 1];
    const float q2 = pos2[p * 3 + 2];
    f16x8 v;
#pragma unroll
    for (int j = 0; j < 8; ++j) {
      const int k = seg + j;
      v[j] = (_Float16)(w2a[32 * 16 + k] * q0 + w2a[33 * 16 + k] * q1 +
                        w2a[34 * 16 + k] * q2);
    }
    *(f16x8*)(vt2 + (size_t)p * 16 + seg) = v;
    return;
  }
  const int lane = threadIdx.x & 63, wid = threadIdx.x >> 6;
  const int col = lane & 15, quad = lane >> 4;
  const int base = (blockIdx.x * 4 + wid) * 16;

  f16x8 B;
#pragma unroll
  for (int j = 0; j < 8; ++j) B[j] = (_Float16)w2a[(quad * 8 + j) * 16 + col];

  float wr[3];
#pragma unroll
  for (int c = 0; c < 3; ++c) wr[c] = w2a[(32 + c) * 16 + col];

  float px[4], py[4], pz[4];
#pragma unroll
  for (int r = 0; r < 4; ++r) {
    const int row = base + quad * 4 + r;
    px[r] = pos3[row * 3 + 0];
    py[r] = pos3[row * 3 + 1];
    pz[r] = pos3[row * 3 + 2];
  }

  f16x8 A = *(const f16x8*)(x3f + (size_t)(base + col) * 32 + quad * 8);
  f32x4 d = {0.f, 0.f, 0.f, 0.f};
  d = mfma16(A, B, d);
  const float bt = b2a[col];
#pragma unroll
  for (int r = 0; r < 4; ++r) {
    const float posterm = px[r] * wr[0] + py[r] * wr[1] + pz[r] * wr[2];
    y3[(size_t)(base + quad * 4 + r) * 16 + col] =
        (_Float16)(d[r] + bt + posterm);
  }
}

// ---------------------------------------------------------------------------
// y2 = x2 @ W3a[:16] + b3a + pos2 @ W3a[16:19]  ([N2][8] f16)
// Fused tail blocks: vt1[p][k] = pos1[p] . W3a[16:19][k]  ([N1][8] f16)
// ---------------------------------------------------------------------------
__global__ __launch_bounds__(256) void y2_kernel(
    const _Float16* __restrict__ x2f, const float* __restrict__ pos2,
    const float* __restrict__ pos1, const float* __restrict__ w3a,
    const float* __restrict__ b3a, _Float16* __restrict__ y2,
    _Float16* __restrict__ vt1) {
  if (blockIdx.x >= 2048) {
    const int p = (blockIdx.x - 2048) * 256 + threadIdx.x;
    const float q0 = pos1[p * 3 + 0];
    const float q1 = pos1[p * 3 + 1];
    const float q2 = pos1[p * 3 + 2];
    f16x8 v;
#pragma unroll
    for (int k = 0; k < 8; ++k)
      v[k] = (_Float16)(w3a[16 * 8 + k] * q0 + w3a[17 * 8 + k] * q1 +
                        w3a[18 * 8 + k] * q2);
    *(f16x8*)(vt1 + (size_t)p * 8) = v;
    return;
  }
  const int lane = threadIdx.x & 63, wid = threadIdx.x >> 6;
  const int col = lane & 15, quad = lane >> 4;
  const int base = (blockIdx.x * 4 + wid) * 16;

  f16x8 B;
#pragma unroll
  for (int j = 0; j < 8; ++j) {
    int k = quad * 8 + j;
    B[j] = (k < 16 && col < 8) ? (_Float16)w3a[k * 8 + col] : (_Float16)0.f;
  }
  f16x8 A = *(const f16x8*)(x2f + (size_t)(base + col) * 16 + (quad & 1) * 8);
  f32x4 d = {0.f, 0.f, 0.f, 0.f};
  d = mfma16(A, B, d);
  if (col < 8) {
    float wr[3];
#pragma unroll
    for (int c = 0; c < 3; ++c) wr[c] = w3a[(16 + c) * 8 + col];
    const float bt = b3a[col];
#pragma unroll
    for (int r = 0; r < 4; ++r) {
      const int row = base + quad * 4 + r;
      const float posterm = pos2[row * 3 + 0] * wr[0] +
                            pos2[row * 3 + 1] * wr[1] +
                            pos2[row * 3 + 2] * wr[2];
      y2[(size_t)row * 8 + col] = (_Float16)(d[r] + bt + posterm);
    }
  }
}

// ---------------------------------------------------------------------------
// Level 3 gather: 2 points/wave via mfma_32x32x16, vtab fold, and a
// COOPERATIVE row gather: 8 lanes load one 128-B y4 row (rows touched once,
// halving TA segment-transactions vs per-lane fragment gathers), staged in a
// wave-private 4 KB LDS tile with XOR swizzle (chunk ^ row&7) so both the
// b128 writes and fragment reads hit the 8-cycle wave64 LDS floor.
// Sync via __syncthreads(): every wave runs exactly 4 iterations (uniform).
// ---------------------------------------------------------------------------
__global__ __launch_bounds__(256) void l3_kernel(
    const _Float16* __restrict__ y4, const _Float16* __restrict__ vt3,
    const int* __restrict__ src3, const float* __restrict__ w1b,
    const float* __restrict__ b1b, _Float16* __restrict__ x3f) {
  __shared__ _Float16 smem[4][32 * 64];  // [wave][row][64ch], swizzled
  const int lane = threadIdx.x & 63, wid = threadIdx.x >> 6;
  const int n = lane & 31;   // B col (out channel) and A row (e + 16h)
  const int kh = lane >> 5;  // k-half
  char* const sw = (char*)smem[wid];

  // B frags: B[ks][j] = w1b[k][n], k = ks*16 + kh*8 + j
  f16x8 Bb[4];
#pragma unroll
  for (int ks = 0; ks < 4; ++ks)
#pragma unroll
    for (int j = 0; j < 8; ++j)
      Bb[ks][j] = (_Float16)w1b[(ks * 16 + kh * 8 + j) * 32 + n];

  // celu-shift fold: biasB = b1b[n] - sum_k w1b[k][n]; k distributed over kh
  float s = 0.f;
#pragma unroll 4
  for (int k = 0; k < 32; ++k) s += w1b[(kh * 32 + k) * 32 + n];
  s += __shfl_xor(s, 32, 64);
  const float biasB = b1b[n] - s;

  const int gwave = blockIdx.x * 4 + wid;
  const int nw = gridDim.x << 2;
  const int chunk = lane & 7;  // 16-B chunk within a 128-B row
  const int rsub = lane >> 3;  // row sub-index within a gather instr (0..7)

#pragma unroll 1
  for (int pb = gwave * 2; pb < N3C; pb += nw * 2) {
    const int s1 = src3[pb * 16 + n];  // lane n holds source row for edge n
    const int p = pb + (n >> 4);

    // cooperative gather: 4 instrs x 8 rows x 128 B, each row touched once
#pragma unroll
    for (int i = 0; i < 4; ++i) {
      const int r = i * 8 + rsub;
      const int sr = __shfl(s1, r, 64);
      const f16x8 d = *(const f16x8*)(y4 + (size_t)sr * 64 + chunk * 8);
      *(f16x8*)(sw + r * 128 + ((chunk * 16) ^ ((r & 7) << 4))) = d;
    }
    __syncthreads();  // uniform trip count across all waves in block

    const _Float16* vrow = vt3 + (size_t)p * 64 + kh * 8;
    f16x8 A[4];
#pragma unroll
    for (int ks = 0; ks < 4; ++ks) {
      const f16x8 yv = *(const f16x8*)(
          sw + n * 128 + ((ks * 32 + kh * 16) ^ ((n & 7) << 4)));
      A[ks] = yv - *(const f16x8*)(vrow + ks * 16);
    }
#pragma unroll
    for (int ks = 0; ks < 4; ++ks) A[ks] = celu8p1(A[ks]);

    f32x16 acc = {};
#pragma unroll
    for (int ks = 0; ks < 4; ++ks) acc = mfma32(A[ks], Bb[ks], acc);

    // regs 0..7 -> rows <16 (point pb), regs 8..15 -> rows >=16 (point pb+1)
    float mA = fmaxf(max3f(max3f(acc[0], acc[1], acc[2]),
                           max3f(acc[3], acc[4], acc[5]), acc[6]), acc[7]);
    float mB = fmaxf(max3f(max3f(acc[8], acc[9], acc[10]),
                           max3f(acc[11], acc[12], acc[13]), acc[14]), acc[15]);
    mA = fmaxf(mA, __shfl_xor(mA, 32, 64));
    mB = fmaxf(mB, __shfl_xor(mB, 32, 64));

    const float mv = kh ? mB : mA;
    x3f[(size_t)(pb + kh) * 32 + n] = (_Float16)celuf(mv + biasB);
    __syncthreads();  // protect tile from next iteration's writes
  }
}

// ---------------------------------------------------------------------------
// Level 2 gather, pair-pipelined: 2 points/wave via mfma_32x32x16, vtab fold.
// (rows are 32 B -> each row already touched exactly once; no LDS staging)
// ---------------------------------------------------------------------------
__device__ __forceinline__ void l2_compute(
    int pr, f16x8 A_in, f16x8 vt, f16x8 Bb, float biasB, int kh, int n,
    _Float16* __restrict__ x2f) {
  f16x8 A = celu8p1(A_in - vt);
  f32x16 acc = {};
  acc = mfma32(A, Bb, acc);

  float mA = fmaxf(max3f(max3f(acc[0], acc[1], acc[2]),
                         max3f(acc[3], acc[4], acc[5]), acc[6]), acc[7]);
  float mB = fmaxf(max3f(max3f(acc[8], acc[9], acc[10]),
                         max3f(acc[11], acc[12], acc[13]), acc[14]), acc[15]);
  mA = fmaxf(mA, __shfl_xor(mA, 32, 64));
  mB = fmaxf(mB, __shfl_xor(mB, 32, 64));

  if (n < 16) {
    const float m = kh ? mB : mA;
    x2f[(size_t)(2 * pr + kh) * 16 + n] = (_Float16)celuf(m + biasB);
  }
}

__global__ __launch_bounds__(256) void l2_kernel(
    const _Float16* __restrict__ y3, const _Float16* __restrict__ vt2,
    const int* __restrict__ src2, const float* __restrict__ w2b,
    const float* __restrict__ b2b, _Float16* __restrict__ x2f) {
  const int lane = threadIdx.x & 63, wid = threadIdx.x >> 6;
  const int n = lane & 31;
  const int e = lane & 15;
  const int h = (lane >> 4) & 1;
  const int kh = lane >> 5;

  f16x8 Bb;
#pragma unroll
  for (int j = 0; j < 8; ++j)
    Bb[j] = (n < 16) ? (_Float16)w2b[(kh * 8 + j) * 16 + n] : (_Float16)0.f;
  // celu-shift fold
  float ws = 0.f;
#pragma unroll
  for (int k = 0; k < 16; ++k) ws += w2b[k * 16 + (n & 15)];
  const float biasB = b2b[n & 15] - ws;

  const int gwave = blockIdx.x * 4 + wid;
  const int nw = gridDim.x << 2;

#pragma unroll 1
  for (int pr = gwave; pr < N2C / 2; pr += 2 * nw) {
    const int pr2 = pr + nw;
    const int pa = 2 * pr + h, pb = 2 * pr2 + h;
    const int sa = src2[pa * 16 + e];
    const int sb = src2[pb * 16 + e];

    f16x8 Aa = *(const f16x8*)(y3 + (size_t)sa * 16 + kh * 8);
    f16x8 Ab = *(const f16x8*)(y3 + (size_t)sb * 16 + kh * 8);
    f16x8 va = *(const f16x8*)(vt2 + (size_t)pa * 16 + kh * 8);
    f16x8 vb = *(const f16x8*)(vt2 + (size_t)pb * 16 + kh * 8);

    l2_compute(pr,  Aa, va, Bb, biasB, kh, n, x2f);
    l2_compute(pr2, Ab, vb, Bb, biasB, kh, n, x2f);
  }
}

// ---------------------------------------------------------------------------
// Level 1 gather, pair-pipelined: 4 points/wave via block-diag mfma_32x32x16,
// vtab position fold. (rows are 16 B -> already one touch per row)
// ---------------------------------------------------------------------------
__device__ __forceinline__ void l1_compute(
    int pb, f16x8 A_in, f16x8 vt, f16x8 Bb, float biasB, float wl, float bl,
    int lane, float* __restrict__ out) {
  f16x8 A = celu8p1(A_in - vt);
  f32x16 acc = {};
  acc = mfma32(A, Bb, acc);

  float mA = fmaxf(max3f(max3f(acc[0], acc[1], acc[2]),
                         max3f(acc[3], acc[4], acc[5]), acc[6]), acc[7]);
  float mB = fmaxf(max3f(max3f(acc[8], acc[9], acc[10]),
                         max3f(acc[11], acc[12], acc[13]), acc[14]), acc[15]);
  mA = fmaxf(mA, __shfl_xor(mA, 32, 64));
  mB = fmaxf(mB, __shfl_xor(mB, 32, 64));

  float tA = celuf(mA + biasB) * wl;  // wl==0 for n>=16
  float tB = celuf(mB + biasB) * wl;
  tA += __shfl_xor(tA, 1, 64);
  tA += __shfl_xor(tA, 2, 64);
  tA += __shfl_xor(tA, 4, 64);
  tB += __shfl_xor(tB, 1, 64);
  tB += __shfl_xor(tB, 2, 64);
  tB += __shfl_xor(tB, 4, 64);
  if (lane == 0) {
    float2 o; o.x = logsigf(tA + bl); o.y = logsigf(tB + bl);
    *(float2*)(out + pb) = o;
  } else if (lane == 8) {
    float2 o; o.x = logsigf(tA + bl); o.y = logsigf(tB + bl);
    *(float2*)(out + pb + 2) = o;
  }
}

__global__ __launch_bounds__(256) void l1_kernel(
    const _Float16* __restrict__ y2, const _Float16* __restrict__ vt1,
    const int* __restrict__ src1, const float* __restrict__ w3b,
    const float* __restrict__ b3b, const float* __restrict__ wlin,
    const float* __restrict__ blin, float* __restrict__ out) {
  const int lane = threadIdx.x & 63, wid = threadIdx.x >> 6;
  const int m = lane & 31;
  const int kh = lane >> 5;
  const int g = 2 * kh + ((lane >> 4) & 1);

  f16x8 Bb;
  const int n = m;
#pragma unroll
  for (int j = 0; j < 8; ++j)
    Bb[j] = (n < 16 && (n >> 3) == kh) ? (_Float16)w3b[j * 8 + (n & 7)]
                                       : (_Float16)0.f;
  float ws = 0.f;
#pragma unroll
  for (int j = 0; j < 8; ++j) ws += w3b[j * 8 + (n & 7)];
  const float biasB = (n < 16) ? b3b[n & 7] - ws : 0.f;
  const float wl = (n < 16) ? wlin[n & 7] : 0.f;
  const float bl = blin[0];

  const int gwave = blockIdx.x * 4 + wid;
  const int nw = gridDim.x << 2;

#pragma unroll 1
  for (int q = gwave; q < N1C / 4; q += 2 * nw) {
    const int q2 = q + nw;
    const int pba = q * 4, pbb = q2 * 4;
    const int pa = pba + g, pb = pbb + g;
    const int sa = src1[q * 64 + lane];
    const int sb = src1[q2 * 64 + lane];

    f16x8 Aa = *(const f16x8*)(y2 + (size_t)sa * 8);
    f16x8 Ab = *(const f16x8*)(y2 + (size_t)sb * 8);
    f16x8 va = *(const f16x8*)(vt1 + (size_t)pa * 8);
    f16x8 vb = *(const f16x8*)(vt1 + (size_t)pb * 8);

    l1_compute(pba, Aa, va, Bb, biasB, wl, bl, lane, out);
    l1_compute(pbb, Ab, vb, Bb, biasB, wl, bl, lane, out);
  }
}

extern "C" void kernel_launch(void* const* d_in, const int* in_sizes, int n_in,
                              void* d_out, int out_size, void* d_ws, size_t ws_size,
                              hipStream_t stream) {
  const float* z_mask = (const float*)d_in[0];
  const float* pos4 = (const float*)d_in[1];
  const float* pos3 = (const float*)d_in[2];
  const float* pos2 = (const float*)d_in[3];
  const float* pos1 = (const float*)d_in[4];
  const float* w1a = (const float*)d_in[9];
  const float* b1a = (const float*)d_in[10];
  const float* w1b = (const float*)d_in[11];
  const float* b1b = (const float*)d_in[12];
  const float* w2a = (const float*)d_in[13];
  const float* b2a = (const float*)d_in[14];
  const float* w2b = (const float*)d_in[15];
  const float* b2b = (const float*)d_in[16];
  const float* w3a = (const float*)d_in[17];
  const float* b3a = (const float*)d_in[18];
  const float* w3b = (const float*)d_in[19];
  const float* b3b = (const float*)d_in[20];
  const float* wlin = (const float*)d_in[21];
  const float* blin = (const float*)d_in[22];
  const int* src3 = (const int*)d_in[23];
  const int* src2 = (const int*)d_in[25];
  const int* src1 = (const int*)d_in[27];

  // ws (16 MB), lifetime-aliased:
  //   y4  [0,4M)   live y4k..l3      | vt3 [4M,12M) live y4k..l3
  //   x3f [12M,16M) live l3..y3k     | y3  [0,2M)   live y3k..l2
  //   vt2 [4M,8M)  live y3k..l2      | x2f [8M,12M) live l2..y2k
  //   y2  [2M,4M)  live y2k..l1      | vt1 [12M,16M) live y2k..l1
  char* w = (char*)d_ws;
  _Float16* y4  = (_Float16*)(w);
  _Float16* vt3 = (_Float16*)(w + (4u << 20));
  _Float16* x3f = (_Float16*)(w + (12u << 20));
  _Float16* y3  = (_Float16*)(w);
  _Float16* vt2 = (_Float16*)(w + (4u << 20));
  _Float16* x2f = (_Float16*)(w + (8u << 20));
  _Float16* y2  = (_Float16*)(w + (2u << 20));
  _Float16* vt1 = (_Float16*)(w + (12u << 20));
  float* out = (float*)d_out;

  y4_kernel<<<2560, 256, 0, stream>>>(z_mask, pos4, pos3, w1a, b1a, y4, vt3);
  l3_kernel<<<2048, 256, 0, stream>>>(y4, vt3, src3, w1b, b1b, x3f);
  y3_kernel<<<2048, 256, 0, stream>>>(x3f, pos3, pos2, w2a, b2a, y3, vt2);
  l2_kernel<<<2048, 256, 0, stream>>>(y3, vt2, src2, w2b, b2b, x2f);
  y2_kernel<<<3072, 256, 0, stream>>>(x2f, pos2, pos1, w3a, b3a, y2, vt1);
  l1_kernel<<<2048, 256, 0, stream>>>(y2, vt1, src1, w3b, b3b,
                                      wlin, blin, out);
}